// Round 18
// baseline (64.467 us; speedup 1.0000x reference)
//
#include <hip/hip_runtime.h>
#include <hip/hip_bf16.h>

typedef __bf16 bf16x4 __attribute__((ext_vector_type(4)));
typedef __bf16 bf16x8 __attribute__((ext_vector_type(8)));
typedef float  f32x4  __attribute__((ext_vector_type(4)));

#define IN_F   4096
#define OUT_F  4096
#define RANK   32

__device__ __forceinline__ bf16x8 cvt8(float4 a, float4 b) {
    bf16x8 r;
    r[0] = (__bf16)a.x; r[1] = (__bf16)a.y; r[2] = (__bf16)a.z; r[3] = (__bf16)a.w;
    r[4] = (__bf16)b.x; r[5] = (__bf16)b.y; r[6] = (__bf16)b.z; r[7] = (__bf16)b.w;
    return r;
}

__device__ __forceinline__ bf16x4 cvt4(float4 a) {
    bf16x4 r;
    r[0] = (__bf16)a.x; r[1] = (__bf16)a.y; r[2] = (__bf16)a.z; r[3] = (__bf16)a.w;
    return r;
}

// ---------------- Kernel 1: Hpart[ks] = (X @ V^T) * S ----------------
// Pattern experiment: every X global load = ONE contiguous 1 KB segment from
// a single row (lane i -> row base + i*16B; the probe's exact pattern, 6.4 TB/s),
// fragment-gather moved into LDS. 512 thr (8 waves), 64 tokens x 1024-feat
// slice (KS=4), 4 chunks x 256 feats. V staged once/block as bf16 (64 KB),
// XL bf16 double-buffered (2x32 KB). XOR swizzle ((row&7)<<3 in bf16 units)
// on ds_write AND ds_read -> <=2-way banks. One __syncthreads per chunk;
// next chunk's loads are VGPR-held so the barrier drains nothing extra.
template <int KS>
__global__ __launch_bounds__(512, 2)
void lora_h(const float* __restrict__ X, const float* __restrict__ S,
            const float* __restrict__ V, float* __restrict__ Hpart)
{
    constexpr int F    = IN_F / KS;     // 1024 feats per block slice
    constexpr int NCHK = F / 256;       // 4 chunks

    __shared__ __bf16 VL[32][1024];     // 64 KB, staged once
    __shared__ __bf16 XL[2][64][256];   // 64 KB, double-buffered per chunk

    const int tid  = threadIdx.x;
    const int wave = tid >> 6;          // 0..7
    const int lane = tid & 63;
    const int r    = lane & 15;
    const int kg   = lane >> 4;

    const int tt = wave & 3;            // token 16-tile
    const int rh = wave >> 2;           // rank half

    const int t0    = blockIdx.x * 64;
    const int fbase = blockIdx.y * F;

    const float sr = S[rh * 16 + r];

    // ---- stage V (whole slice) once: 16 x 1KB single-row loads per wave ----
    {
        float4 vr[16];
        #pragma unroll
        for (int t = 0; t < 16; ++t) {
            const int row = wave * 4 + (t >> 2), q = t & 3;
            vr[t] = *reinterpret_cast<const float4*>(
                V + (size_t)row * IN_F + fbase + q * 256 + lane * 4);
        }
        #pragma unroll
        for (int t = 0; t < 16; ++t) {
            const int row = wave * 4 + (t >> 2), q = t & 3;
            const int e = (q * 256 + lane * 4) ^ ((row & 7) << 3);
            *reinterpret_cast<bf16x4*>(&VL[row][e]) = cvt4(vr[t]);
        }
    }

    float4 xr[8];                       // in-flight X chunk (1 row per instr)
    auto xload = [&](int c) {
        const int fc = fbase + ((c + blockIdx.x) & (NCHK - 1)) * 256;
        #pragma unroll
        for (int t = 0; t < 8; ++t) {
            const int row = wave * 8 + t;
            xr[t] = *reinterpret_cast<const float4*>(
                X + (size_t)(t0 + row) * IN_F + fc + lane * 4);
        }
    };
    auto xwrite = [&](int cur) {
        #pragma unroll
        for (int t = 0; t < 8; ++t) {
            const int row = wave * 8 + t;
            const int e = (lane * 4) ^ ((row & 7) << 3);
            *reinterpret_cast<bf16x4*>(&XL[cur][row][e]) = cvt4(xr[t]);
        }
    };

    f32x4 acc = {0.f, 0.f, 0.f, 0.f};   // this wave's (tt, rh) 16x16 tile

    auto compute = [&](int c, int cur) {
        const int sw    = (r & 7) << 3;
        const int vbase = ((c + blockIdx.x) & (NCHK - 1)) * 256;
        #pragma unroll
        for (int s = 0; s < 8; ++s) {
            bf16x8 xb = *reinterpret_cast<const bf16x8*>(
                &XL[cur][tt * 16 + r][(s * 32 + kg * 8) ^ sw]);
            bf16x8 vb = *reinterpret_cast<const bf16x8*>(
                &VL[rh * 16 + r][(vbase + s * 32 + kg * 8) ^ sw]);
            // A = X (m = token), B = V (n = rank-in-half), K = 32 feats
            acc = __builtin_amdgcn_mfma_f32_16x16x32_bf16(xb, vb, acc, 0, 0, 0);
        }
    };

    xload(0);
    xwrite(0);
    __syncthreads();

    for (int c = 0; c < NCHK; ++c) {
        if (c + 1 < NCHK) xload(c + 1);         // issue-early (VGPR-held)
        compute(c, c & 1);                       // consume current LDS buffer
        if (c + 1 < NCHK) {
            xwrite((c + 1) & 1);                 // other buffer: no race w/ compute
            __syncthreads();                     // visibility for next compute
        }
    }

    // D: token = tt*16 + kg*4 + j, rank = rh*16 + r. Direct global store.
    float* Hq = Hpart + ((size_t)blockIdx.y * 8192 + t0) * RANK;
    #pragma unroll
    for (int j = 0; j < 4; ++j) {
        const int tok = tt * 16 + kg * 4 + j;
        Hq[(size_t)tok * RANK + rh * 16 + r] = acc[j] * sr;
    }
}

// ---------------- Fallback (never taken when ws >= 5 MB): naive H ----------------
__global__ __launch_bounds__(256)
void lora_h_naive(const float* __restrict__ X, const float* __restrict__ S,
                  const float* __restrict__ V, float* __restrict__ H)
{
    const int idx = blockIdx.x * 256 + threadIdx.x;   // 262144 = 8192*32
    const int tok = idx >> 5, rk = idx & 31;
    float acc = 0.f;
    for (int f = 0; f < IN_F; ++f)
        acc += X[(size_t)tok * IN_F + f] * V[(size_t)rk * IN_F + f];
    H[idx] = acc * S[rk];
}

// ---------------- Kernel 1.5: H = sum_k Hpart[k] ----------------
template <int NKS>
__global__ __launch_bounds__(256)
void lora_hred(const float* __restrict__ Hpart, float* __restrict__ H)
{
    const int idx = blockIdx.x * 256 + threadIdx.x;   // float4 idx, 65536
    const float4* hp = reinterpret_cast<const float4*>(Hpart);
    float4 v = hp[idx];
    #pragma unroll
    for (int k = 1; k < NKS; ++k) {
        float4 p = hp[(size_t)k * 65536 + idx];
        v.x += p.x; v.y += p.y; v.z += p.z; v.w += p.w;
    }
    reinterpret_cast<float4*>(H)[idx] = v;
}

// ---------------- Kernel 2 (proven ~9.5 µs): Out = H @ U^T ----------------
__global__ __launch_bounds__(256, 4)
void lora_out(const float* __restrict__ H, const float* __restrict__ U,
              float* __restrict__ Out)
{
    __shared__ float Hs[32][33];

    const int tid  = threadIdx.x;
    const int wave = tid >> 6;
    const int lane = tid & 63;
    const int r    = lane & 15;
    const int kg   = lane >> 4;

    const int tt = blockIdx.x >> 2;
    const int cq = blockIdx.x & 3;
    const int t0 = tt * 32;

    {
        float4 v = reinterpret_cast<const float4*>(H + (size_t)t0 * RANK)[tid];
        const int tok = tid >> 3;
        const int rr  = (tid & 7) * 4;
        Hs[tok][rr] = v.x; Hs[tok][rr + 1] = v.y;
        Hs[tok][rr + 2] = v.z; Hs[tok][rr + 3] = v.w;
    }
    __syncthreads();

    bf16x8 hb[2];
    #pragma unroll
    for (int a = 0; a < 2; ++a)
        #pragma unroll
        for (int j = 0; j < 8; ++j) hb[a][j] = (__bf16)Hs[a * 16 + r][kg * 8 + j];

    const int wc0 = cq * 1024 + wave * 256;

    #pragma unroll
    for (int g = 0; g < 4; ++g) {
        float4 u0[4], u1[4];
        #pragma unroll
        for (int b = 0; b < 4; ++b) {
            const float4* up = reinterpret_cast<const float4*>(
                U + (size_t)(wc0 + g * 64 + b * 16 + r) * RANK + kg * 8);
            u0[b] = up[0];
            u1[b] = up[1];
        }
        #pragma unroll
        for (int b = 0; b < 4; ++b) {
            bf16x8 ub = cvt8(u0[b], u1[b]);
            #pragma unroll
            for (int a = 0; a < 2; ++a) {
                f32x4 d = {0.f, 0.f, 0.f, 0.f};
                d = __builtin_amdgcn_mfma_f32_16x16x32_bf16(ub, hb[a], d, 0, 0, 0);
                *reinterpret_cast<float4*>(
                    Out + (size_t)(t0 + a * 16 + r) * OUT_F
                        + wc0 + g * 64 + b * 16 + kg * 4)
                    = *reinterpret_cast<float4*>(&d);
            }
        }
    }
}

extern "C" void kernel_launch(void* const* d_in, const int* in_sizes, int n_in,
                              void* d_out, int out_size, void* d_ws, size_t ws_size,
                              hipStream_t stream) {
    const float* X = (const float*)d_in[0];
    const float* U = (const float*)d_in[1];
    const float* S = (const float*)d_in[2];
    const float* V = (const float*)d_in[3];
    float* Out = (float*)d_out;

    float* H     = (float*)d_ws;                 // 1 MB reduced H
    float* Hpart = (float*)d_ws + 262144;        // 4 MB partials (KS=4)

    if (ws_size >= (size_t)5 * 1024 * 1024) {
        lora_h<4><<<dim3(128, 4), 512, 0, stream>>>(X, S, V, Hpart);
        lora_hred<4><<<256, 256, 0, stream>>>(Hpart, H);
        lora_out<<<1024, 256, 0, stream>>>(H, U, Out);
    } else {
        lora_h_naive<<<1024, 256, 0, stream>>>(X, S, V, H);
        lora_out<<<1024, 256, 0, stream>>>(H, U, Out);
    }
}